// Round 8
// baseline (130.504 us; speedup 1.0000x reference)
//
#include <hip/hip_runtime.h>

// Problem constants (fixed by the reference).
#define BATCH 16384
#define DIN   128
#define HIDN  16
#define NNODE 255
#define NLEAF 256
#define TR    16          // batch rows per tree block

typedef _Float16 half8 __attribute__((ext_vector_type(8)));
typedef _Float16 half4 __attribute__((ext_vector_type(4)));
typedef float   float4v __attribute__((ext_vector_type(4)));

// ---------------- combined pack kernel ----------------
// blocks 0..1023: pack x -> f16 B-operand fragments
//   lane L holds B[k=(L>>4)*8+j][n=L&15] (n=batch, k=din); ws: [bt][kc][lane] half8
// blocks 1024..1278: pack W1[n] -> f16 A-operand fragments (LDS-staged)
//   lane L holds A[m=L&15][k=(L>>4)*8+j] (m=hidden, k=din); plus W2[n] -> f16
__global__ __launch_bounds__(256) void k_pack(const float* __restrict__ x, const float* __restrict__ w1,
                                              const float* __restrict__ w2,
                                              half8* __restrict__ xp, half8* __restrict__ w1p,
                                              _Float16* __restrict__ w2h) {
    __shared__ float w[DIN * 17];
    int t = threadIdx.x;
    if (blockIdx.x < 1024) {
        int gid  = blockIdx.x * 256 + t;
        int lane = gid & 63;
        int kc   = (gid >> 6) & 3;
        int bt   = gid >> 8;
        const float4* src = (const float4*)(x + (size_t)(bt * 16 + (lane & 15)) * DIN + kc * 32 + ((lane >> 4) * 8));
        float4 v0 = src[0], v1 = src[1];
        half8 v;
        v[0] = (_Float16)v0.x; v[1] = (_Float16)v0.y; v[2] = (_Float16)v0.z; v[3] = (_Float16)v0.w;
        v[4] = (_Float16)v1.x; v[5] = (_Float16)v1.y; v[6] = (_Float16)v1.z; v[7] = (_Float16)v1.w;
        xp[gid] = v;
    } else {
        int n = blockIdx.x - 1024;
        const float4* src = (const float4*)(w1 + (size_t)n * (DIN * HIDN)) + t * 2;
        float4 a0 = src[0], a1 = src[1];
        int base = t * 8;
#pragma unroll
        for (int e = 0; e < 4; ++e) {
            int idx0 = base + e, idx1 = base + 4 + e;
            w[(idx0 >> 4) * 17 + (idx0 & 15)] = (&a0.x)[e];
            w[(idx1 >> 4) * 17 + (idx1 & 15)] = (&a1.x)[e];
        }
        __syncthreads();
        int L  = t & 63;
        int kc = t >> 6;
        int m  = L & 15;
        int k0 = kc * 32 + (L >> 4) * 8;
        half8 v;
#pragma unroll
        for (int j = 0; j < 8; ++j) v[j] = (_Float16)w[(k0 + j) * 17 + m];
        w1p[(size_t)n * 256 + t] = v;
        if (t < HIDN) w2h[n * HIDN + t] = (_Float16)w2[n * HIDN + t];
    }
}

// ---------------- MLP: p_ws[n][b] = LOGIT via double MFMA, software-pipelined ----------------
// Grid (64, 51): 3264 blocks (3x R7) -> 12.75 waves/SIMD offered; 5 nodes/block keeps
// total w1p/xp L2 traffic identical (reuse = tiles-per-wave, unchanged at 4).
// Node loop fully unrolled with explicit next-node prefetch: {w1p, b1, w2, b2} for node
// i+1 issue before node i's 20 MFMAs, so L2 latency (~200cyc) hides under compute.
__global__ __launch_bounds__(256, 4) void k_mlp(const half8* __restrict__ xp, const half8* __restrict__ w1p,
                                                const float* __restrict__ b1, const _Float16* __restrict__ w2h,
                                                const float* __restrict__ b2, float* __restrict__ p_ws) {
    int wv   = threadIdx.x >> 6;
    int lane = threadIdx.x & 63;
    int q    = lane >> 4;
    int bt0  = blockIdx.x * 16 + wv * 4;
    int n0   = blockIdx.y * 5;

    half8 bq[4][4];
#pragma unroll
    for (int t = 0; t < 4; ++t)
#pragma unroll
        for (int kc = 0; kc < 4; ++kc)
            bq[t][kc] = xp[(size_t)((bt0 + t) * 4 + kc) * 64 + lane];
    asm volatile("" ::: "memory");

    // prologue: load node n0's fragments
    half8 a_cur[4];
#pragma unroll
    for (int kc = 0; kc < 4; ++kc) a_cur[kc] = w1p[(size_t)(n0 * 4 + kc) * 64 + lane];
    float4 b1_cur = ((const float4*)(b1 + n0 * HIDN))[q];
    half4  a2_cur = *(const half4*)(w2h + n0 * HIDN + q * 4);
    float  b2_cur = b2[n0];

#pragma unroll
    for (int i = 0; i < 5; ++i) {
        int n = n0 + i;
        // prefetch node i+1 while node i computes
        half8 a_nxt[4]; float4 b1_nxt; half4 a2_nxt; float b2_nxt;
        if (i < 4) {
            int m = n + 1;
#pragma unroll
            for (int kc = 0; kc < 4; ++kc) a_nxt[kc] = w1p[(size_t)(m * 4 + kc) * 64 + lane];
            b1_nxt = ((const float4*)(b1 + m * HIDN))[q];
            a2_nxt = *(const half4*)(w2h + m * HIDN + q * 4);
            b2_nxt = b2[m];
        }
#pragma unroll
        for (int t = 0; t < 4; ++t) {
            float4v acc = {b1_cur.x, b1_cur.y, b1_cur.z, b1_cur.w};
#pragma unroll
            for (int kc = 0; kc < 4; ++kc)
                acc = __builtin_amdgcn_mfma_f32_16x16x32_f16(a_cur[kc], bq[t][kc], acc, 0, 0, 0);
            half4 rb;
#pragma unroll
            for (int r = 0; r < 4; ++r) rb[r] = (_Float16)fmaxf(acc[r], 0.f);
            float4v acc2 = {b2_cur, b2_cur, b2_cur, b2_cur};
            acc2 = __builtin_amdgcn_mfma_f32_16x16x16f16(a2_cur, rb, acc2, 0, 0, 0);
            if (lane < 16)
                p_ws[(size_t)n * BATCH + (bt0 + t) * 16 + lane] = acc2[0];  // full 64B line
        }
        if (i < 4) {
#pragma unroll
            for (int kc = 0; kc < 4; ++kc) a_cur[kc] = a_nxt[kc];
            b1_cur = b1_nxt; a2_cur = a2_nxt; b2_cur = b2_nxt;
        }
    }
}

// ---------------- tree scan: sigmoid + all outputs, coalesced ----------------
// Block = 256 thr, 16 batch rows, LDS 16.4 KB (grid 1024 -> 4 blocks/CU).
__global__ __launch_bounds__(256) void k_tree(const float* __restrict__ p_ws, const float* __restrict__ leaf,
                                              float* __restrict__ h_out, float* __restrict__ pp_out,
                                              float* __restrict__ p_out, float* __restrict__ nr_out) {
    __shared__ float sp[TR][NNODE + 2];           // stride 257
    int wv   = threadIdx.x >> 6;
    int lane = threadIdx.x & 63;
    int b0   = blockIdx.x * TR;
    int t    = threadIdx.x;

    // stage + sigmoid: 255*16 = 4080 logits
#pragma unroll
    for (int i = 0; i < 16; ++i) {
        int idx = i * 256 + t;
        if (idx < NNODE * TR) {
            int n = idx >> 4, bl = idx & 15;
            float lg = p_ws[(size_t)n * BATCH + b0 + bl];
            sp[bl][n] = __builtin_amdgcn_rcpf(1.f + __builtin_amdgcn_exp2f(-1.44269504088896f * lg));
        }
    }
    __syncthreads();

    // coalesced p_out copy
    for (int r = 0; r < TR; ++r)
        if (t < NNODE)
            p_out[(size_t)(b0 + r) * NNODE + t] = sp[r][t];

    // tree scan: 4 rows per wave; lane L owns leaves 4L..4L+3
    for (int rr = 0; rr < 4; ++rr) {
        int i = wv * 4 + rr;
        int b = b0 + i;
        const float* P = &sp[i][0];
        float* nr = nr_out + (size_t)b * NNODE;

        float pref = 1.f;
#pragma unroll
        for (int l = 0; l < 6; ++l) {
            if ((lane & ((1 << (6 - l)) - 1)) == 0) nr[(1 << l) - 1 + (lane >> (6 - l))] = pref;
            float pv  = P[(1 << l) - 1 + (lane >> (6 - l))];
            int  bit  = (lane >> (5 - l)) & 1;
            pref *= bit ? pv : (1.f - pv);
        }
        nr[63 + lane] = pref;
        float p6 = P[63 + lane];
        float pl = pref * (1.f - p6);
        float pr = pref * p6;
        nr[127 + 2 * lane] = pl;
        nr[128 + 2 * lane] = pr;
        float p7a = P[127 + 2 * lane];
        float p7b = P[128 + 2 * lane];
        float4 pp;
        pp.x = pl * (1.f - p7a);
        pp.y = pl * p7a;
        pp.z = pr * (1.f - p7b);
        pp.w = pr * p7b;
        *(float4*)(pp_out + (size_t)b * NLEAF + 4 * lane) = pp;
        const float4 lf = *(const float4*)(leaf + 4 * lane);
        float hs = pp.x * lf.x + pp.y * lf.y + pp.z * lf.z + pp.w * lf.w;
#pragma unroll
        for (int off = 1; off < 64; off <<= 1) hs += __shfl_xor(hs, off, 64);
        if (lane == 0) h_out[b] = hs;
    }
}

extern "C" void kernel_launch(void* const* d_in, const int* in_sizes, int n_in,
                              void* d_out, int out_size, void* d_ws, size_t ws_size,
                              hipStream_t stream) {
    const float* x    = (const float*)d_in[0];
    const float* W1   = (const float*)d_in[1];
    const float* b1   = (const float*)d_in[2];
    const float* W2   = (const float*)d_in[3];
    const float* b2   = (const float*)d_in[4];
    const float* leaf = (const float*)d_in[5];

    float* out    = (float*)d_out;
    float* h_out  = out;                                   // [16384]
    float* pp_out = out + BATCH;                           // [16384*256]
    float* p_out  = pp_out + (size_t)BATCH * NLEAF;        // [16384*255]
    float* nr_out = p_out + (size_t)BATCH * NNODE;         // [16384*255]

    // workspace: 4 MB xp + ~1 MB w1p + 8 KB w2h + 16.7 MB logits
    half8*    xp   = (half8*)d_ws;
    half8*    w1p  = xp + (size_t)1024 * 4 * 64;
    _Float16* w2h  = (_Float16*)(w1p + (size_t)NNODE * 256);
    float*    p_ws = (float*)((char*)w2h + ((NNODE * HIDN * 2 + 255) & ~255));

    hipLaunchKernelGGL(k_pack, dim3(1024 + NNODE), dim3(256), 0, stream, x, W1, W2, xp, w1p, w2h);
    hipLaunchKernelGGL(k_mlp,  dim3(64, 51), dim3(256), 0, stream, xp, w1p, b1, w2h, b2, p_ws);
    hipLaunchKernelGGL(k_tree, dim3(BATCH / TR), dim3(256), 0, stream,
                       p_ws, leaf, h_out, pp_out, p_out, nr_out);
}